// Round 2
// baseline (258.856 us; speedup 1.0000x reference)
//
#include <hip/hip_runtime.h>

namespace {

constexpr int B  = 128;
constexpr int A  = 8732;
constexpr int NC = 21;
constexpr int THREADS = 256;
constexpr int ABLK = (A + THREADS - 1) / THREADS;  // 35 blocks per row

__device__ __forceinline__ float waveReduceSum(float v) {
#pragma unroll
    for (int off = 32; off; off >>= 1) v += __shfl_xor(v, off, 64);
    return v;
}
__device__ __forceinline__ int waveReduceSumI(int v) {
#pragma unroll
    for (int off = 32; off; off >>= 1) v += __shfl_xor(v, off, 64);
    return v;
}

// ws layout: acc[0]=loc_loss, acc[1]=cls_loss ; npos[B] per-row positive counts
__global__ void init_kernel(float* __restrict__ acc, int* __restrict__ npos) {
    int t = threadIdx.x;
    if (t < 2) acc[t] = 0.f;
    if (t < B) npos[t] = 0;
}

__global__ __launch_bounds__(THREADS) void main_kernel(
    const float* __restrict__ locp,
    const float* __restrict__ loct,
    const float* __restrict__ clsp,
    const int*   __restrict__ tgt,
    float* __restrict__ acc,
    int*   __restrict__ npos)
{
    const int b = blockIdx.y;
    const int a = blockIdx.x * THREADS + threadIdx.x;

    float ce = 0.f, locv = 0.f;
    int posc = 0;

    if (a < A) {
        const long i = (long)b * A + a;
        const int t = tgt[i];

        // ---- cross entropy: ce = logsumexp(x) - x[tgt] ----
        const float* __restrict__ x = clsp + i * (long)NC;
        float xs[NC];
#pragma unroll
        for (int c = 0; c < NC; ++c) xs[c] = x[c];
        float m = xs[0];
#pragma unroll
        for (int c = 1; c < NC; ++c) m = fmaxf(m, xs[c]);
        float s = 0.f;
#pragma unroll
        for (int c = 0; c < NC; ++c) s += __expf(xs[c] - m);
        const int tc = t < 0 ? 0 : (t > NC - 1 ? NC - 1 : t);
        ce = (t < 0) ? 0.f : (m + __logf(s) - xs[tc]);

        // ---- masked smooth-L1 over 4 coords ----
        if (t > 0) {
            posc = 1;
            const float4 lp = *(const float4*)(locp + i * 4);
            const float4 lt = *(const float4*)(loct + i * 4);
            float d;
            d = fabsf(lp.x - lt.x); locv += (d < 1.f) ? 0.5f * d * d : d - 0.5f;
            d = fabsf(lp.y - lt.y); locv += (d < 1.f) ? 0.5f * d * d : d - 0.5f;
            d = fabsf(lp.z - lt.z); locv += (d < 1.f) ? 0.5f * d * d : d - 0.5f;
            d = fabsf(lp.w - lt.w); locv += (d < 1.f) ? 0.5f * d * d : d - 0.5f;
        }
    }

    // block reduction (4 waves of 64)
    __shared__ float sLoc[4], sCls[4];
    __shared__ int sPos[4];
    const int wid = threadIdx.x >> 6, lane = threadIdx.x & 63;
    float wl = waveReduceSum(locv);
    float wc = waveReduceSum(ce);
    int   wp = waveReduceSumI(posc);
    if (lane == 0) { sLoc[wid] = wl; sCls[wid] = wc; sPos[wid] = wp; }
    __syncthreads();
    if (threadIdx.x == 0) {
        float L = sLoc[0] + sLoc[1] + sLoc[2] + sLoc[3];
        float C = sCls[0] + sCls[1] + sCls[2] + sCls[3];
        int   P = sPos[0] + sPos[1] + sPos[2] + sPos[3];
        atomicAdd(&acc[0], L);
        atomicAdd(&acc[1], C);   // optimistic: sum of ALL ce (all-selected fast path)
        atomicAdd(&npos[b], P);
    }
}

// Correction for rows where hard-negative mining actually excludes anchors
// (3*num_pos < A). For the reference input distribution this never triggers
// (P(pos) = 20/21 -> 3*num_pos ~ 25k >> 8732), but keep it for correctness.
__global__ __launch_bounds__(THREADS) void mining_kernel(
    const float* __restrict__ clsp,
    const int*   __restrict__ tgt,
    const int*   __restrict__ npos,
    float* __restrict__ acc)
{
    const int b = blockIdx.x;
    const int K = 3 * npos[b];
    if (K >= A) return;  // everything selected; main_kernel's sum is exact

    __shared__ float mined[A];  // 34.9 KB
    for (int i = threadIdx.x; i < A; i += THREADS) {
        const long idx = (long)b * A + i;
        const int t = tgt[idx];
        float ce = 0.f;
        if (t >= 0) {
            const float* __restrict__ x = clsp + idx * (long)NC;
            float m = x[0];
            for (int c = 1; c < NC; ++c) m = fmaxf(m, x[c]);
            float s = 0.f;
            for (int c = 0; c < NC; ++c) s += __expf(x[c] - m);
            const int tc = t > NC - 1 ? NC - 1 : t;
            ce = m + __logf(s) - x[tc];
        }
        mined[i] = (t > 0) ? 0.f : -ce;  // matches ce*(pos-1)
    }
    __syncthreads();

    float corr = 0.f;  // subtract ce of unselected anchors
    for (int i = threadIdx.x; i < A; i += THREADS) {
        const int t = tgt[(long)b * A + i];
        if (t > 0) continue;  // positives always selected
        const float mi = mined[i];
        int rank = 0;  // stable-sort rank: #{j: key_j < key_i} with (value, idx) lex order
        for (int j = 0; j < A; ++j) {
            const float mj = mined[j];
            rank += (mj < mi || (mj == mi && j < i)) ? 1 : 0;
        }
        if (rank >= K) corr += mi;  // mi = -ce_i
    }

    __shared__ float sC[4];
    const int wid = threadIdx.x >> 6, lane = threadIdx.x & 63;
    float wcorr = waveReduceSum(corr);
    if (lane == 0) sC[wid] = wcorr;
    __syncthreads();
    if (threadIdx.x == 0) atomicAdd(&acc[1], sC[0] + sC[1] + sC[2] + sC[3]);
}

__global__ void finalize_kernel(const float* __restrict__ acc,
                                const int* __restrict__ npos,
                                float* __restrict__ out)
{
    if (threadIdx.x == 0) {
        int np = 0;
        for (int i = 0; i < B; ++i) np += npos[i];
        out[0] = (acc[0] + acc[1]) / (float)np;
    }
}

}  // namespace

extern "C" void kernel_launch(void* const* d_in, const int* in_sizes, int n_in,
                              void* d_out, int out_size, void* d_ws, size_t ws_size,
                              hipStream_t stream) {
    const float* locp = (const float*)d_in[0];
    const float* loct = (const float*)d_in[1];
    const float* clsp = (const float*)d_in[2];
    const int*   tgt  = (const int*)d_in[3];

    float* acc  = (float*)d_ws;
    int*   npos = (int*)((char*)d_ws + 2 * sizeof(float));
    float* out  = (float*)d_out;

    hipLaunchKernelGGL(init_kernel, dim3(1), dim3(256), 0, stream, acc, npos);
    hipLaunchKernelGGL(main_kernel, dim3(ABLK, B), dim3(THREADS), 0, stream,
                       locp, loct, clsp, tgt, acc, npos);
    hipLaunchKernelGGL(mining_kernel, dim3(B), dim3(THREADS), 0, stream,
                       clsp, tgt, npos, acc);
    hipLaunchKernelGGL(finalize_kernel, dim3(1), dim3(64), 0, stream, acc, npos, out);
}